// Round 11
// baseline (188.304 us; speedup 1.0000x reference)
//
#include <hip/hip_runtime.h>
#include <hip/hip_bf16.h>

#define BB 64      // batch
#define NN 2048    // nodes
#define CC 64      // channels
#define DD 16      // embed

typedef __attribute__((ext_vector_type(8))) short bf16x8;   // 8 bf16 = 4 VGPR
typedef __attribute__((ext_vector_type(4))) float f32x4;

__device__ __forceinline__ ushort f2bf(float f) {          // RNE f32->bf16
  unsigned u = __float_as_uint(f);
  u += 0x7fffu + ((u >> 16) & 1u);
  return (ushort)(u >> 16);
}
__device__ __forceinline__ float b2f(ushort h) {
  return __uint_as_float(((unsigned)h) << 16);
}

// async global->LDS, 16B per lane; LDS dest is wave-uniform base + lane*16
#define GLOAD16(g, l)                                                 \
  __builtin_amdgcn_global_load_lds(                                   \
      (const __attribute__((address_space(1))) void*)(g),             \
      (__attribute__((address_space(3))) void*)(l), 16, 0, 0)

// ---------------------------------------------------------------------------
// Kernel 0: Xt[b][c][m] (bf16) = X[b][m][c] (f32)   -- one-time transpose
// ---------------------------------------------------------------------------
__global__ __launch_bounds__(256) void transpose_x_kernel(
    const float* __restrict__ X, ushort* __restrict__ Xt) {
  const int b = blockIdx.y;
  const int m0 = blockIdx.x * 256;
  const int t = threadIdx.x;
  __shared__ ushort xs[256 * 64];  // byte = m*128 + ((2c)^((m&7)<<4))

#pragma unroll
  for (int it = 0; it < 16; ++it) {
    const int idx = it * 256 + t;
    const int m = idx >> 4;
    const int cq = (idx & 15) * 4;
    float4 v = *(const float4*)&X[(size_t)b * NN * CC + (size_t)(m0 + m) * CC + cq];
    ushort4 h;
    h.x = f2bf(v.x); h.y = f2bf(v.y); h.z = f2bf(v.z); h.w = f2bf(v.w);
    *(ushort4*)((char*)xs + m * 128 + ((cq * 2) ^ ((m & 7) << 4))) = h;
  }
  __syncthreads();

  const int c = t >> 2;
  const int mb = (t & 3) * 64;
#pragma unroll
  for (int s = 0; s < 8; ++s) {
    unsigned w0 = 0, w1 = 0, w2 = 0, w3 = 0;
#pragma unroll
    for (int j = 0; j < 8; ++j) {
      const int m = mb + s * 8 + j;
      const ushort hv =
          *(const ushort*)((const char*)xs + m * 128 + ((2 * c) ^ ((m & 7) << 4)));
      const unsigned uv = (unsigned)hv << ((j & 1) * 16);
      if (j < 2) w0 |= uv; else if (j < 4) w1 |= uv;
      else if (j < 6) w2 |= uv; else w3 |= uv;
    }
    uint4 pk = {w0, w1, w2, w3};
    *(uint4*)&Xt[(size_t)b * CC * NN + (size_t)c * NN + m0 + mb + s * 8] = pk;
  }
}

// ---------------------------------------------------------------------------
// Kernel 0b: Wpt[d][o][ki] (bf16) = Wp[d][ki][o] (f32)   -- one-time, 393 KB
// ---------------------------------------------------------------------------
__global__ __launch_bounds__(256) void wpt_kernel(
    const float* __restrict__ Wp, ushort* __restrict__ Wpt) {
  const int g = blockIdx.x * 256 + threadIdx.x;   // 0..24575
  const int d = g / 1536;
  const int rem = g % 1536;
  const int o = rem / 24;
  const int ki0 = (rem % 24) * 8;
  bf16x8 h;
#pragma unroll
  for (int j = 0; j < 8; ++j)
    h[j] = (short)f2bf(Wp[d * 12288 + (ki0 + j) * 64 + o]);
  *(bf16x8*)&Wpt[d * 12288 + o * 192 + ki0] = h;
}

// ---------------------------------------------------------------------------
// Kernel 1: S[n,m] = softmax_m(relu(E[n]·E[m]))  -> bf16
// ---------------------------------------------------------------------------
__global__ __launch_bounds__(256) void supports_kernel(
    const float* __restrict__ E, ushort* __restrict__ S) {
  const int n = blockIdx.x;
  const int t = threadIdx.x;

  __shared__ float en[DD];
  if (t < DD) en[t] = E[n * DD + t];
  __syncthreads();

  float e[DD];
#pragma unroll
  for (int d = 0; d < DD; ++d) e[d] = en[d];

  float vals[8];
  float vmax = 0.f;
#pragma unroll
  for (int j = 0; j < 8; ++j) {
    const int m = j * 256 + t;
    const float4* Em = (const float4*)&E[m * DD];
    float4 v0 = Em[0], v1 = Em[1], v2 = Em[2], v3 = Em[3];
    float dot = e[0]*v0.x + e[1]*v0.y + e[2]*v0.z + e[3]*v0.w
              + e[4]*v1.x + e[5]*v1.y + e[6]*v1.z + e[7]*v1.w
              + e[8]*v2.x + e[9]*v2.y + e[10]*v2.z + e[11]*v2.w
              + e[12]*v3.x + e[13]*v3.y + e[14]*v3.z + e[15]*v3.w;
    dot = fmaxf(dot, 0.f);
    vals[j] = dot;
    vmax = fmaxf(vmax, dot);
  }

  __shared__ float red[256];
  red[t] = vmax;
  __syncthreads();
  for (int s = 128; s > 0; s >>= 1) {
    if (t < s) red[t] = fmaxf(red[t], red[t + s]);
    __syncthreads();
  }
  vmax = red[0];
  __syncthreads();

  float sum = 0.f;
#pragma unroll
  for (int j = 0; j < 8; ++j) {
    vals[j] = __expf(vals[j] - vmax);
    sum += vals[j];
  }
  red[t] = sum;
  __syncthreads();
  for (int s = 128; s > 0; s >>= 1) {
    if (t < s) red[t] += red[t + s];
    __syncthreads();
  }
  const float inv = 1.f / red[0];

#pragma unroll
  for (int j = 0; j < 8; ++j)
    S[(size_t)n * NN + j * 256 + t] = f2bf(vals[j] * inv);
}

// ---------------------------------------------------------------------------
// Kernel 2: MFMA spmm, transposed form.
//   Yt[b][c][n] = sum_m At[b][c][m] * S[n][m]
// NEW: 128 thr / 2 waves, wave tile 64x128 (acc[4][8]) -- 25% fewer
// ds_read_b128 per FLOP than 64x64 waves. Single-buffer 40 KB LDS ->
// 4 blocks/CU; stage -> vmcnt(0) -> barrier -> compute -> barrier.
// ---------------------------------------------------------------------------
__global__ __launch_bounds__(128) void spmm_t_kernel(
    const ushort* __restrict__ At, const ushort* __restrict__ S,
    ushort* __restrict__ Yt, ushort* __restrict__ Yn) {
  const int b  = blockIdx.x;
  const int n0 = blockIdx.y * 256;
  const int t  = threadIdx.x;
  const int w  = t >> 6;               // 0..1
  const int l  = t & 63;

  __shared__ ushort Als[64 * 64];      // 8 KB  : [c][64k] swizzled
  __shared__ ushort Bls[256 * 64];     // 32 KB : [r][64k] swizzled

  const char* Abase = (const char*)(At + (size_t)b * CC * NN);
  const char* Sbase = (const char*)S + (size_t)n0 * (NN * 2);

  f32x4 acc[4][8];
#pragma unroll
  for (int i = 0; i < 4; ++i)
#pragma unroll
    for (int j = 0; j < 8; ++j) acc[i][j] = (f32x4)0.f;

  const int lkb = (l & 7) * 16;        // byte offset within 128B row chunk
  const int lrw = w * 8 + (l >> 3);    // 16 rows per 2KB issue-line (128 thr)

  auto stage = [&](int mt) {
#pragma unroll
    for (int q = 0; q < 4; ++q) {      // A: 64 rows -> 4 issue-lines
      const int row = q * 16 + lrw;
      GLOAD16(Abase + (size_t)row * (NN * 2) + mt * 2 + (lkb ^ ((row & 7) << 4)),
              (char*)Als + q * 2048 + w * 1024);
    }
#pragma unroll
    for (int q = 0; q < 16; ++q) {     // B: 256 rows -> 16 issue-lines
      const int row = q * 16 + lrw;
      GLOAD16(Sbase + (size_t)row * (NN * 2) + mt * 2 + (lkb ^ ((row & 7) << 4)),
              (char*)Bls + q * 2048 + w * 1024);
    }
  };

  stage(0);
  for (int it = 0; it < 32; ++it) {
    asm volatile("s_waitcnt vmcnt(0)" ::: "memory");
    __builtin_amdgcn_s_barrier();
    __builtin_amdgcn_sched_barrier(0);

#pragma unroll
    for (int kk = 0; kk < 2; ++kk) {
      const int kb = kk * 64 + (l >> 4) * 16;
      bf16x8 a[4];
#pragma unroll
      for (int cf = 0; cf < 4; ++cf) {
        const int c = cf * 16 + (l & 15);
        a[cf] = *(const bf16x8*)((const char*)Als + c * 128 +
                                 (kb ^ ((c & 7) << 4)));
      }
#pragma unroll
      for (int ng = 0; ng < 2; ++ng) {       // two groups of 4 n-frags
        bf16x8 bv[4];
#pragma unroll
        for (int nf = 0; nf < 4; ++nf) {
          const int r = w * 128 + ng * 64 + nf * 16 + (l & 15);
          bv[nf] = *(const bf16x8*)((const char*)Bls + r * 128 +
                                    (kb ^ ((r & 7) << 4)));
        }
#pragma unroll
        for (int cf = 0; cf < 4; ++cf)
#pragma unroll
          for (int nf = 0; nf < 4; ++nf)
            acc[cf][ng * 4 + nf] = __builtin_amdgcn_mfma_f32_16x16x32_bf16(
                a[cf], bv[nf], acc[cf][ng * 4 + nf], 0, 0, 0);
      }
    }

    __builtin_amdgcn_sched_barrier(0);
    __builtin_amdgcn_s_barrier();
    if (it < 31) stage((it + 1) * 64);
  }

  const int nw = n0 + w * 128;
#pragma unroll
  for (int cf = 0; cf < 4; ++cf) {
#pragma unroll
    for (int nf = 0; nf < 8; ++nf) {
      const int n = nw + nf * 16 + (l & 15);
      const int cb = cf * 16 + (l >> 4) * 4;
      ushort h0 = f2bf(acc[cf][nf][0]);
      ushort h1 = f2bf(acc[cf][nf][1]);
      ushort h2 = f2bf(acc[cf][nf][2]);
      ushort h3 = f2bf(acc[cf][nf][3]);
      if (Yt) {
        ushort* p = Yt + (size_t)b * CC * NN + (size_t)cb * NN + n;
        p[0] = h0; p[NN] = h1; p[2 * NN] = h2; p[3 * NN] = h3;
      }
      if (Yn) {
        ushort4 pk = {h0, h1, h2, h3};
        *(ushort4*)(Yn + (size_t)b * NN * CC + (size_t)n * CC + cb) = pk;
      }
    }
  }
}

// ---------------------------------------------------------------------------
// Kernel 3: final contraction, TWO nodes per block (512 threads).
// (Round-5 version verbatim -- measured best.)
// ---------------------------------------------------------------------------
__global__ __launch_bounds__(512) void out_kernel(
    const float* __restrict__ E, const ushort* __restrict__ Wpt,
    const float* __restrict__ Bp, const float* __restrict__ X,
    const ushort* __restrict__ Y1n, const ushort* __restrict__ Y1t,
    const ushort* __restrict__ Y2n, float* __restrict__ Out) {
  const int n0 = blockIdx.x * 2;
  const int t = threadIdx.x;

  __shared__ ushort Wt[2][64 * 192];   // 48 KB, [o][ki], byte^=((o&7)<<4)
  __shared__ ushort xg[2][64 * 192];   // 48 KB, [b][ki]
  __shared__ float bsh[2][64];
  __shared__ float esh[2][DD];

  if (t < 2 * DD) esh[t >> 4][t & 15] = E[(n0 + (t >> 4)) * DD + (t & 15)];
  __syncthreads();
  float ea[DD], eb[DD];
#pragma unroll
  for (int d = 0; d < DD; ++d) { ea[d] = esh[0][d]; eb[d] = esh[1][d]; }

  if (t < 128) {
    const int node = t >> 6, o = t & 63;
    const float* e = node ? eb : ea;
    float bsum = 0.f;
#pragma unroll
    for (int d = 0; d < DD; ++d) bsum = fmaf(e[d], Bp[d * 64 + o], bsum);
    bsh[node][o] = bsum;
  }

  // ---- W-build: linear sweep, 3 chunks x 8 KB; one load -> two nodes ----
#pragma unroll
  for (int it = 0; it < 3; ++it) {
    const int boff = it * 8192 + t * 16;   // linear byte in 24576B block
    float acc0[8] = {}, acc1[8] = {};
#pragma unroll
    for (int d = 0; d < DD; ++d) {
      bf16x8 wv = *(const bf16x8*)((const char*)Wpt + d * 24576 + boff);
#pragma unroll
      for (int u = 0; u < 8; ++u) {
        const float f = b2f((ushort)wv[u]);
        acc0[u] = fmaf(ea[d], f, acc0[u]);
        acc1[u] = fmaf(eb[d], f, acc1[u]);
      }
    }
    bf16x8 h0, h1;
#pragma unroll
    for (int u = 0; u < 8; ++u) {
      h0[u] = (short)f2bf(acc0[u]);
      h1[u] = (short)f2bf(acc1[u]);
    }
    const int o = boff / 384;
    const int sw = (boff % 384) ^ ((o & 7) << 4);
    *(bf16x8*)((char*)Wt[0] + o * 384 + sw) = h0;
    *(bf16x8*)((char*)Wt[1] + o * 384 + sw) = h1;
  }

  // ---- build xg[node][b][ki]: k0 = x, k1 = y1, k2 = 2*y2 - x ----
  {
    const int node = t >> 8, tt = t & 255;
    const int b = tt >> 2, i0 = (tt & 3) * 16;
    const int n = n0 + node;
    const size_t NC = (size_t)NN * CC;
    const size_t gbase = (size_t)b * NC + (size_t)n * CC + i0;
    char* xgn = (char*)xg[node];
    float xv[16];
#pragma unroll
    for (int j = 0; j < 4; ++j) {
      float4 v = *(const float4*)&X[gbase + j * 4];
      xv[j * 4 + 0] = v.x; xv[j * 4 + 1] = v.y;
      xv[j * 4 + 2] = v.z; xv[j * 4 + 3] = v.w;
    }
#pragma unroll
    for (int h = 0; h < 2; ++h) {
      bf16x8 hv;
#pragma unroll
      for (int u = 0; u < 8; ++u) hv[u] = (short)f2bf(xv[h * 8 + u]);
      const int ki = i0 + h * 8;
      *(bf16x8*)(xgn + b * 384 + ((ki * 2) ^ ((b & 7) << 4))) = hv;
    }
    if (Y1n) {
#pragma unroll
      for (int h = 0; h < 2; ++h) {
        bf16x8 hv = *(const bf16x8*)&Y1n[gbase + h * 8];
        const int ki = 64 + i0 + h * 8;
        *(bf16x8*)(xgn + b * 384 + ((ki * 2) ^ ((b & 7) << 4))) = hv;
      }
    } else {
#pragma unroll
      for (int h = 0; h < 2; ++h) {
        bf16x8 hv;
#pragma unroll
        for (int u = 0; u < 8; ++u)
          hv[u] = (short)Y1t[(size_t)b * NC + (size_t)(i0 + h * 8 + u) * NN + n];
        const int ki = 64 + i0 + h * 8;
        *(bf16x8*)(xgn + b * 384 + ((ki * 2) ^ ((b & 7) << 4))) = hv;
      }
    }
#pragma unroll
    for (int h = 0; h < 2; ++h) {
      bf16x8 y2 = *(const bf16x8*)&Y2n[gbase + h * 8];
      bf16x8 hv;
#pragma unroll
      for (int u = 0; u < 8; ++u)
        hv[u] = (short)f2bf(2.f * b2f((ushort)y2[u]) - xv[h * 8 + u]);
      const int ki = 128 + i0 + h * 8;
      *(bf16x8*)(xgn + b * 384 + ((ki * 2) ^ ((b & 7) << 4))) = hv;
    }
  }
  __syncthreads();

  // ---- MFMA: wave w -> node w>>2, 32x32 quadrant w&3, K=192 ----
  const int w8 = t >> 6, l = t & 63;
  const int node = w8 >> 2, q = w8 & 3;
  const int br = (q & 1) * 32, oc = (q >> 1) * 32;
  const char* xgn = (const char*)xg[node];
  const char* wtn = (const char*)Wt[node];

  f32x4 acc[2][2];
#pragma unroll
  for (int i = 0; i < 2; ++i)
#pragma unroll
    for (int j = 0; j < 2; ++j) acc[i][j] = (f32x4)0.f;

#pragma unroll
  for (int s = 0; s < 6; ++s) {
    const int kb = s * 64 + (l >> 4) * 16;
    bf16x8 av[2], bv[2];
#pragma unroll
    for (int i = 0; i < 2; ++i) {
      const int row = br + i * 16 + (l & 15);
      av[i] = *(const bf16x8*)(xgn + row * 384 + (kb ^ ((row & 7) << 4)));
    }
#pragma unroll
    for (int j = 0; j < 2; ++j) {
      const int row = oc + j * 16 + (l & 15);
      bv[j] = *(const bf16x8*)(wtn + row * 384 + (kb ^ ((row & 7) << 4)));
    }
#pragma unroll
    for (int i = 0; i < 2; ++i)
#pragma unroll
      for (int j = 0; j < 2; ++j)
        acc[i][j] = __builtin_amdgcn_mfma_f32_16x16x32_bf16(av[i], bv[j],
                                                            acc[i][j], 0, 0, 0);
  }

  // ---- epilogue ----
  const size_t NC = (size_t)NN * CC;
  const int n = n0 + node;
#pragma unroll
  for (int i = 0; i < 2; ++i) {
#pragma unroll
    for (int j = 0; j < 2; ++j) {
      const int o = oc + j * 16 + (l & 15);
      const int bb = br + i * 16 + (l >> 4) * 4;
      const float bo = bsh[node][o];
#pragma unroll
      for (int r = 0; r < 4; ++r)
        Out[(size_t)(bb + r) * NC + (size_t)n * CC + o] = acc[i][j][r] + bo;
    }
  }
}

// ---------------------------------------------------------------------------
extern "C" void kernel_launch(void* const* d_in, const int* in_sizes, int n_in,
                              void* d_out, int out_size, void* d_ws, size_t ws_size,
                              hipStream_t stream) {
  const float* x  = (const float*)d_in[1];
  const float* E  = (const float*)d_in[2];
  const float* Wp = (const float*)d_in[3];
  const float* Bp = (const float*)d_in[4];
  float* out = (float*)d_out;

  // ws: S 8MB | Xt/Y2n 16MB | Y1t 16MB | Wpt 384KB | [Y1n 16MB]
  const size_t szS  = (size_t)NN * NN * 2;
  const size_t szY  = (size_t)BB * NN * CC * 2;
  const size_t szWp = (size_t)DD * 3 * CC * CC * 2;   // 393,216 B
  ushort* Sb  = (ushort*)d_ws;
  ushort* Xt  = (ushort*)((char*)d_ws + szS);
  ushort* Y1t = (ushort*)((char*)d_ws + szS + szY);
  ushort* Wpt = (ushort*)((char*)d_ws + szS + 2 * szY);
  ushort* Y1n = (ushort*)((char*)d_ws + szS + 2 * szY + szWp);
  ushort* Y2n = Xt;  // Xt dead after spmm1
  const bool haveY1n = ws_size >= szS + 3 * szY + szWp;

  transpose_x_kernel<<<dim3(NN / 256, BB), 256, 0, stream>>>(x, Xt);
  wpt_kernel<<<96, 256, 0, stream>>>(Wp, Wpt);
  supports_kernel<<<NN, 256, 0, stream>>>(E, Sb);

  dim3 g2(BB, NN / 256);  // x=b innermost: S-tile shared across 64 blocks
  spmm_t_kernel<<<g2, 128, 0, stream>>>(Xt, Sb, Y1t, haveY1n ? Y1n : nullptr);
  spmm_t_kernel<<<g2, 128, 0, stream>>>(Y1t, Sb, nullptr, Y2n);

  out_kernel<<<NN / 2, 512, 0, stream>>>(E, Wpt, Bp, x, haveY1n ? Y1n : nullptr,
                                         Y1t, Y2n, out);
}

// Round 12
// 172.554 us; speedup vs baseline: 1.0913x; 1.0913x over previous
//
#include <hip/hip_runtime.h>
#include <hip/hip_bf16.h>

#define BB 64      // batch
#define NN 2048    // nodes
#define CC 64      // channels
#define DD 16      // embed

typedef __attribute__((ext_vector_type(8))) short bf16x8;   // 8 bf16 = 4 VGPR
typedef __attribute__((ext_vector_type(4))) float f32x4;

__device__ __forceinline__ ushort f2bf(float f) {          // RNE f32->bf16
  unsigned u = __float_as_uint(f);
  u += 0x7fffu + ((u >> 16) & 1u);
  return (ushort)(u >> 16);
}
__device__ __forceinline__ float b2f(ushort h) {
  return __uint_as_float(((unsigned)h) << 16);
}

// async global->LDS, 16B per lane; LDS dest is wave-uniform base + lane*16
#define GLOAD16(g, l)                                                 \
  __builtin_amdgcn_global_load_lds(                                   \
      (const __attribute__((address_space(1))) void*)(g),             \
      (__attribute__((address_space(3))) void*)(l), 16, 0, 0)

// ---------------------------------------------------------------------------
// Kernel 0: Xt[b][c][m] (bf16) = X[b][m][c] (f32)   -- one-time transpose
// ---------------------------------------------------------------------------
__global__ __launch_bounds__(256) void transpose_x_kernel(
    const float* __restrict__ X, ushort* __restrict__ Xt) {
  const int b = blockIdx.y;
  const int m0 = blockIdx.x * 256;
  const int t = threadIdx.x;
  __shared__ ushort xs[256 * 64];  // byte = m*128 + ((2c)^((m&7)<<4))

#pragma unroll
  for (int it = 0; it < 16; ++it) {
    const int idx = it * 256 + t;
    const int m = idx >> 4;
    const int cq = (idx & 15) * 4;
    float4 v = *(const float4*)&X[(size_t)b * NN * CC + (size_t)(m0 + m) * CC + cq];
    ushort4 h;
    h.x = f2bf(v.x); h.y = f2bf(v.y); h.z = f2bf(v.z); h.w = f2bf(v.w);
    *(ushort4*)((char*)xs + m * 128 + ((cq * 2) ^ ((m & 7) << 4))) = h;
  }
  __syncthreads();

  const int c = t >> 2;
  const int mb = (t & 3) * 64;
#pragma unroll
  for (int s = 0; s < 8; ++s) {
    unsigned w0 = 0, w1 = 0, w2 = 0, w3 = 0;
#pragma unroll
    for (int j = 0; j < 8; ++j) {
      const int m = mb + s * 8 + j;
      const ushort hv =
          *(const ushort*)((const char*)xs + m * 128 + ((2 * c) ^ ((m & 7) << 4)));
      const unsigned uv = (unsigned)hv << ((j & 1) * 16);
      if (j < 2) w0 |= uv; else if (j < 4) w1 |= uv;
      else if (j < 6) w2 |= uv; else w3 |= uv;
    }
    uint4 pk = {w0, w1, w2, w3};
    *(uint4*)&Xt[(size_t)b * CC * NN + (size_t)c * NN + m0 + mb + s * 8] = pk;
  }
}

// ---------------------------------------------------------------------------
// Kernel 0b: Wpt[d][o][ki] (bf16) = Wp[d][ki][o] (f32)   -- one-time, 393 KB
// ---------------------------------------------------------------------------
__global__ __launch_bounds__(256) void wpt_kernel(
    const float* __restrict__ Wp, ushort* __restrict__ Wpt) {
  const int g = blockIdx.x * 256 + threadIdx.x;   // 0..24575
  const int d = g / 1536;
  const int rem = g % 1536;
  const int o = rem / 24;
  const int ki0 = (rem % 24) * 8;
  bf16x8 h;
#pragma unroll
  for (int j = 0; j < 8; ++j)
    h[j] = (short)f2bf(Wp[d * 12288 + (ki0 + j) * 64 + o]);
  *(bf16x8*)&Wpt[d * 12288 + o * 192 + ki0] = h;
}

// ---------------------------------------------------------------------------
// Kernel 1: S[n,m] = softmax_m(relu(E[n]·E[m]))  -> bf16
// ---------------------------------------------------------------------------
__global__ __launch_bounds__(256) void supports_kernel(
    const float* __restrict__ E, ushort* __restrict__ S) {
  const int n = blockIdx.x;
  const int t = threadIdx.x;

  __shared__ float en[DD];
  if (t < DD) en[t] = E[n * DD + t];
  __syncthreads();

  float e[DD];
#pragma unroll
  for (int d = 0; d < DD; ++d) e[d] = en[d];

  float vals[8];
  float vmax = 0.f;
#pragma unroll
  for (int j = 0; j < 8; ++j) {
    const int m = j * 256 + t;
    const float4* Em = (const float4*)&E[m * DD];
    float4 v0 = Em[0], v1 = Em[1], v2 = Em[2], v3 = Em[3];
    float dot = e[0]*v0.x + e[1]*v0.y + e[2]*v0.z + e[3]*v0.w
              + e[4]*v1.x + e[5]*v1.y + e[6]*v1.z + e[7]*v1.w
              + e[8]*v2.x + e[9]*v2.y + e[10]*v2.z + e[11]*v2.w
              + e[12]*v3.x + e[13]*v3.y + e[14]*v3.z + e[15]*v3.w;
    dot = fmaxf(dot, 0.f);
    vals[j] = dot;
    vmax = fmaxf(vmax, dot);
  }

  __shared__ float red[256];
  red[t] = vmax;
  __syncthreads();
  for (int s = 128; s > 0; s >>= 1) {
    if (t < s) red[t] = fmaxf(red[t], red[t + s]);
    __syncthreads();
  }
  vmax = red[0];
  __syncthreads();

  float sum = 0.f;
#pragma unroll
  for (int j = 0; j < 8; ++j) {
    vals[j] = __expf(vals[j] - vmax);
    sum += vals[j];
  }
  red[t] = sum;
  __syncthreads();
  for (int s = 128; s > 0; s >>= 1) {
    if (t < s) red[t] += red[t + s];
    __syncthreads();
  }
  const float inv = 1.f / red[0];

#pragma unroll
  for (int j = 0; j < 8; ++j)
    S[(size_t)n * NN + j * 256 + t] = f2bf(vals[j] * inv);
}

// ---------------------------------------------------------------------------
// Kernel 2: MFMA spmm, transposed form, 2-phase double-buffered pipeline.
//   Yt[b][c][n] = sum_m At[b][c][m] * S[n][m]
// Measured-best structure (round 5): 256 thr / 4 waves, tile 64x256, dbuf
// 80 KB, counted vmcnt(10) (never 0 in-loop), 2 blocks/CU; tail iteration
// wraps to a dead prefetch so the vmcnt count is uniform.
// ---------------------------------------------------------------------------
__global__ __launch_bounds__(256) void spmm_t_kernel(
    const ushort* __restrict__ At, const ushort* __restrict__ S,
    ushort* __restrict__ Yt, ushort* __restrict__ Yn) {
  const int b  = blockIdx.x;
  const int n0 = blockIdx.y * 256;
  const int t  = threadIdx.x;
  const int w  = t >> 6;
  const int l  = t & 63;

  __shared__ ushort Als[2][64 * 64];    // 2 x 8 KB
  __shared__ ushort Bls[2][256 * 64];   // 2 x 32 KB   (total 80 KB)

  const char* Abase = (const char*)(At + (size_t)b * CC * NN);
  const char* Sbase = (const char*)S + (size_t)n0 * (NN * 2);

  f32x4 acc[4][4];
#pragma unroll
  for (int i = 0; i < 4; ++i)
#pragma unroll
    for (int j = 0; j < 4; ++j) acc[i][j] = (f32x4)0.f;

  const int lkb = (l & 7) * 16;
  const int lrw = w * 8 + (l >> 3);

  auto stage = [&](int buf, int mt) {
#pragma unroll
    for (int q = 0; q < 2; ++q) {
      const int row = q * 32 + lrw;
      GLOAD16(Abase + (size_t)row * (NN * 2) + mt * 2 + (lkb ^ ((row & 7) << 4)),
              (char*)Als[buf] + q * 4096 + w * 1024);
    }
#pragma unroll
    for (int q = 0; q < 8; ++q) {
      const int row = q * 32 + lrw;
      GLOAD16(Sbase + (size_t)row * (NN * 2) + mt * 2 + (lkb ^ ((row & 7) << 4)),
              (char*)Bls[buf] + q * 4096 + w * 1024);
    }
  };

  stage(0, 0);
  int cur = 0;
  for (int it = 0; it < 32; ++it) {
    const int nmt = ((it + 1) & 31) * 64;   // it=31 wraps: dead prefetch
    stage(cur ^ 1, nmt);
    asm volatile("s_waitcnt vmcnt(10)" ::: "memory");
    __builtin_amdgcn_s_barrier();
    __builtin_amdgcn_sched_barrier(0);

#pragma unroll
    for (int kk = 0; kk < 2; ++kk) {
      const int kb = kk * 64 + (l >> 4) * 16;
      bf16x8 a[4], bv[4];
#pragma unroll
      for (int cf = 0; cf < 4; ++cf) {
        const int c = cf * 16 + (l & 15);
        a[cf] = *(const bf16x8*)((const char*)Als[cur] + c * 128 +
                                 (kb ^ ((c & 7) << 4)));
      }
#pragma unroll
      for (int nf = 0; nf < 4; ++nf) {
        const int r = w * 64 + nf * 16 + (l & 15);
        bv[nf] = *(const bf16x8*)((const char*)Bls[cur] + r * 128 +
                                  (kb ^ ((r & 7) << 4)));
      }
#pragma unroll
      for (int cf = 0; cf < 4; ++cf)
#pragma unroll
        for (int nf = 0; nf < 4; ++nf)
          acc[cf][nf] = __builtin_amdgcn_mfma_f32_16x16x32_bf16(
              a[cf], bv[nf], acc[cf][nf], 0, 0, 0);
    }

    __builtin_amdgcn_sched_barrier(0);
    __builtin_amdgcn_s_barrier();
    cur ^= 1;
  }

  const int nw = n0 + w * 64;
#pragma unroll
  for (int cf = 0; cf < 4; ++cf) {
#pragma unroll
    for (int nf = 0; nf < 4; ++nf) {
      const int n = nw + nf * 16 + (l & 15);
      const int cb = cf * 16 + (l >> 4) * 4;
      ushort h0 = f2bf(acc[cf][nf][0]);
      ushort h1 = f2bf(acc[cf][nf][1]);
      ushort h2 = f2bf(acc[cf][nf][2]);
      ushort h3 = f2bf(acc[cf][nf][3]);
      if (Yt) {
        ushort* p = Yt + (size_t)b * CC * NN + (size_t)cb * NN + n;
        p[0] = h0; p[NN] = h1; p[2 * NN] = h2; p[3 * NN] = h3;
      }
      if (Yn) {
        ushort4 pk = {h0, h1, h2, h3};
        *(ushort4*)(Yn + (size_t)b * NN * CC + (size_t)n * CC + cb) = pk;
      }
    }
  }
}

// ---------------------------------------------------------------------------
// Kernel 3: final contraction, TWO nodes per block (512 threads).
// Each Wpt vector load feeds BOTH nodes' W accumulation -> halves Wpt L2
// traffic. 8 waves: wave w handles node w>>2, quadrant w&3.
// ---------------------------------------------------------------------------
__global__ __launch_bounds__(512) void out_kernel(
    const float* __restrict__ E, const ushort* __restrict__ Wpt,
    const float* __restrict__ Bp, const float* __restrict__ X,
    const ushort* __restrict__ Y1n, const ushort* __restrict__ Y1t,
    const ushort* __restrict__ Y2n, float* __restrict__ Out) {
  const int n0 = blockIdx.x * 2;
  const int t = threadIdx.x;

  __shared__ ushort Wt[2][64 * 192];   // 48 KB, [o][ki], byte^=((o&7)<<4)
  __shared__ ushort xg[2][64 * 192];   // 48 KB, [b][ki]
  __shared__ float bsh[2][64];
  __shared__ float esh[2][DD];

  if (t < 2 * DD) esh[t >> 4][t & 15] = E[(n0 + (t >> 4)) * DD + (t & 15)];
  __syncthreads();
  float ea[DD], eb[DD];
#pragma unroll
  for (int d = 0; d < DD; ++d) { ea[d] = esh[0][d]; eb[d] = esh[1][d]; }

  if (t < 128) {
    const int node = t >> 6, o = t & 63;
    const float* e = node ? eb : ea;
    float bsum = 0.f;
#pragma unroll
    for (int d = 0; d < DD; ++d) bsum = fmaf(e[d], Bp[d * 64 + o], bsum);
    bsh[node][o] = bsum;
  }

  // ---- W-build: linear sweep, 3 chunks x 8 KB; one load -> two nodes ----
#pragma unroll
  for (int it = 0; it < 3; ++it) {
    const int boff = it * 8192 + t * 16;   // linear byte in 24576B block
    float acc0[8] = {}, acc1[8] = {};
#pragma unroll
    for (int d = 0; d < DD; ++d) {
      bf16x8 wv = *(const bf16x8*)((const char*)Wpt + d * 24576 + boff);
#pragma unroll
      for (int u = 0; u < 8; ++u) {
        const float f = b2f((ushort)wv[u]);
        acc0[u] = fmaf(ea[d], f, acc0[u]);
        acc1[u] = fmaf(eb[d], f, acc1[u]);
      }
    }
    bf16x8 h0, h1;
#pragma unroll
    for (int u = 0; u < 8; ++u) {
      h0[u] = (short)f2bf(acc0[u]);
      h1[u] = (short)f2bf(acc1[u]);
    }
    const int o = boff / 384;
    const int sw = (boff % 384) ^ ((o & 7) << 4);
    *(bf16x8*)((char*)Wt[0] + o * 384 + sw) = h0;
    *(bf16x8*)((char*)Wt[1] + o * 384 + sw) = h1;
  }

  // ---- build xg[node][b][ki]: k0 = x, k1 = y1, k2 = 2*y2 - x ----
  {
    const int node = t >> 8, tt = t & 255;
    const int b = tt >> 2, i0 = (tt & 3) * 16;
    const int n = n0 + node;
    const size_t NC = (size_t)NN * CC;
    const size_t gbase = (size_t)b * NC + (size_t)n * CC + i0;
    char* xgn = (char*)xg[node];
    float xv[16];
#pragma unroll
    for (int j = 0; j < 4; ++j) {
      float4 v = *(const float4*)&X[gbase + j * 4];
      xv[j * 4 + 0] = v.x; xv[j * 4 + 1] = v.y;
      xv[j * 4 + 2] = v.z; xv[j * 4 + 3] = v.w;
    }
#pragma unroll
    for (int h = 0; h < 2; ++h) {
      bf16x8 hv;
#pragma unroll
      for (int u = 0; u < 8; ++u) hv[u] = (short)f2bf(xv[h * 8 + u]);
      const int ki = i0 + h * 8;
      *(bf16x8*)(xgn + b * 384 + ((ki * 2) ^ ((b & 7) << 4))) = hv;
    }
    if (Y1n) {
#pragma unroll
      for (int h = 0; h < 2; ++h) {
        bf16x8 hv = *(const bf16x8*)&Y1n[gbase + h * 8];
        const int ki = 64 + i0 + h * 8;
        *(bf16x8*)(xgn + b * 384 + ((ki * 2) ^ ((b & 7) << 4))) = hv;
      }
    } else {
#pragma unroll
      for (int h = 0; h < 2; ++h) {
        bf16x8 hv;
#pragma unroll
        for (int u = 0; u < 8; ++u)
          hv[u] = (short)Y1t[(size_t)b * NC + (size_t)(i0 + h * 8 + u) * NN + n];
        const int ki = 64 + i0 + h * 8;
        *(bf16x8*)(xgn + b * 384 + ((ki * 2) ^ ((b & 7) << 4))) = hv;
      }
    }
#pragma unroll
    for (int h = 0; h < 2; ++h) {
      bf16x8 y2 = *(const bf16x8*)&Y2n[gbase + h * 8];
      bf16x8 hv;
#pragma unroll
      for (int u = 0; u < 8; ++u)
        hv[u] = (short)f2bf(2.f * b2f((ushort)y2[u]) - xv[h * 8 + u]);
      const int ki = 128 + i0 + h * 8;
      *(bf16x8*)(xgn + b * 384 + ((ki * 2) ^ ((b & 7) << 4))) = hv;
    }
  }
  __syncthreads();

  // ---- MFMA: wave w -> node w>>2, 32x32 quadrant w&3, K=192 ----
  const int w8 = t >> 6, l = t & 63;
  const int node = w8 >> 2, q = w8 & 3;
  const int br = (q & 1) * 32, oc = (q >> 1) * 32;
  const char* xgn = (const char*)xg[node];
  const char* wtn = (const char*)Wt[node];

  f32x4 acc[2][2];
#pragma unroll
  for (int i = 0; i < 2; ++i)
#pragma unroll
    for (int j = 0; j < 2; ++j) acc[i][j] = (f32x4)0.f;

#pragma unroll
  for (int s = 0; s < 6; ++s) {
    const int kb = s * 64 + (l >> 4) * 16;
    bf16x8 av[2], bv[2];
#pragma unroll
    for (int i = 0; i < 2; ++i) {
      const int row = br + i * 16 + (l & 15);
      av[i] = *(const bf16x8*)(xgn + row * 384 + (kb ^ ((row & 7) << 4)));
    }
#pragma unroll
    for (int j = 0; j < 2; ++j) {
      const int row = oc + j * 16 + (l & 15);
      bv[j] = *(const bf16x8*)(wtn + row * 384 + (kb ^ ((row & 7) << 4)));
    }
#pragma unroll
    for (int i = 0; i < 2; ++i)
#pragma unroll
      for (int j = 0; j < 2; ++j)
        acc[i][j] = __builtin_amdgcn_mfma_f32_16x16x32_bf16(av[i], bv[j],
                                                            acc[i][j], 0, 0, 0);
  }

  // ---- epilogue ----
  const size_t NC = (size_t)NN * CC;
  const int n = n0 + node;
#pragma unroll
  for (int i = 0; i < 2; ++i) {
#pragma unroll
    for (int j = 0; j < 2; ++j) {
      const int o = oc + j * 16 + (l & 15);
      const int bb = br + i * 16 + (l >> 4) * 4;
      const float bo = bsh[node][o];
#pragma unroll
      for (int r = 0; r < 4; ++r)
        Out[(size_t)(bb + r) * NC + (size_t)n * CC + o] = acc[i][j][r] + bo;
    }
  }
}

// ---------------------------------------------------------------------------
extern "C" void kernel_launch(void* const* d_in, const int* in_sizes, int n_in,
                              void* d_out, int out_size, void* d_ws, size_t ws_size,
                              hipStream_t stream) {
  const float* x  = (const float*)d_in[1];
  const float* E  = (const float*)d_in[2];
  const float* Wp = (const float*)d_in[3];
  const float* Bp = (const float*)d_in[4];
  float* out = (float*)d_out;

  // ws: S 8MB | Xt/Y2n 16MB | Y1t 16MB | Wpt 384KB | [Y1n 16MB]
  const size_t szS  = (size_t)NN * NN * 2;
  const size_t szY  = (size_t)BB * NN * CC * 2;
  const size_t szWp = (size_t)DD * 3 * CC * CC * 2;   // 393,216 B
  ushort* Sb  = (ushort*)d_ws;
  ushort* Xt  = (ushort*)((char*)d_ws + szS);
  ushort* Y1t = (ushort*)((char*)d_ws + szS + szY);
  ushort* Wpt = (ushort*)((char*)d_ws + szS + 2 * szY);
  ushort* Y1n = (ushort*)((char*)d_ws + szS + 2 * szY + szWp);
  ushort* Y2n = Xt;  // Xt dead after spmm1
  const bool haveY1n = ws_size >= szS + 3 * szY + szWp;

  transpose_x_kernel<<<dim3(NN / 256, BB), 256, 0, stream>>>(x, Xt);
  wpt_kernel<<<96, 256, 0, stream>>>(Wp, Wpt);
  supports_kernel<<<NN, 256, 0, stream>>>(E, Sb);

  dim3 g2(BB, NN / 256);  // x=b innermost: S-tile shared across 64 blocks
  spmm_t_kernel<<<g2, 256, 0, stream>>>(Xt, Sb, Y1t, haveY1n ? Y1n : nullptr);
  spmm_t_kernel<<<g2, 256, 0, stream>>>(Y1t, Sb, nullptr, Y2n);

  out_kernel<<<NN / 2, 512, 0, stream>>>(E, Wpt, Bp, x, haveY1n ? Y1n : nullptr,
                                         Y1t, Y2n, out);
}